// Round 2
// baseline (74.020 us; speedup 1.0000x reference)
//
#include <hip/hip_runtime.h>

// AllZeroDigitalFilter: time-varying FIR with linearly-interpolated coefficients.
//   out[b,t] = sum_{k=0..255} x[b,t-k] * ((1-f)*h[b,n,k] + f*h[b,n1,k])
//   n = t/80, f = (t%80)/80, n1 = min(n+1, N-1), x[neg] = 0
// B=8, N=800, P=80, T=64000, TAPS=256.
//
// v2: all-b128 LDS reads + register shift-window for x.
//   - RR=4 outputs/thread, 320 threads/block, 16 frames/block -> 400 blocks, 2000 waves.
//   - per 4-tap iter: 1 float4 x load (sliding window) + 2 float4 h loads
//     (broadcast across 20-thread frame groups; rows offset 4 banks) -> 32 FMAs.

#define TAPS 256
#define PP 80
#define BB 8
#define NN 800
#define TT (NN * PP)
#define FPB 16                    // frames per block
#define TPF 20                    // threads per frame
#define RR 4                      // outputs per thread
#define NTHREADS (FPB * TPF)      // 320
#define HSTRIDE 260               // floats; 1040 B row stride: 16B-aligned, +4 bank shift
#define XB 260                    // sx index of x[t0]; multiple of 4
#define XLEN (FPB * PP + XB + 4)  // 1544 floats
#define CHUNKS (NN / FPB)         // 50

__global__ __launch_bounds__(NTHREADS) void azdf_kernel(
    const float* __restrict__ x, const float* __restrict__ h,
    float* __restrict__ out)
{
    __shared__ float sh[(FPB + 1) * HSTRIDE];   // 17*260*4 = 17680 B
    __shared__ float sx[XLEN];                  // 6176 B

    const int tid = threadIdx.x;
    const int blk = blockIdx.x;
    const int b   = blk / CHUNKS;
    const int nc  = blk % CHUNKS;
    const int n0  = nc * FPB;
    const int t0  = n0 * PP;

    // ---- stage h rows n0 .. n0+FPB (clamped), float4 ----
    const float* hb = h + (size_t)b * NN * TAPS;
    for (int i = tid; i < (FPB + 1) * (TAPS / 4); i += NTHREADS) {
        int r  = i >> 6;           // row 0..16
        int q  = i & 63;           // float4 index in row
        int gr = n0 + r;
        if (gr > NN - 1) gr = NN - 1;
        float4 v = ((const float4*)(hb + (size_t)gr * TAPS))[q];
        ((float4*)(sh + r * HSTRIDE))[q] = v;
    }

    // ---- stage x: sx[i] = x[t0 + i - XB], zero-padded ----
    const float* xb = x + (size_t)b * TT;
    for (int i = tid; i < XLEN; i += NTHREADS) {
        int g = t0 + i - XB;
        sx[i] = (g >= 0 && g < TT) ? xb[g] : 0.0f;
    }
    __syncthreads();

    // ---- compute: thread -> 4 consecutive outputs t = t0 + 4*tid + r ----
    const int lf    = tid / TPF;            // local frame 0..15
    const int p0    = (tid % TPF) * RR;     // phase of output r=0
    const int xbase = XB + 4 * tid;         // sx index of x[t] for r=0 (mult of 4)
    const float* hA = sh + lf * HSTRIDE;
    const float* hB = hA + HSTRIDE;

    float acc0[RR], acc1[RR];
    #pragma unroll
    for (int r = 0; r < RR; ++r) { acc0[r] = 0.0f; acc1[r] = 0.0f; }

    // register window W[j] = sx[xbase - k - 4 + j], j=0..7  (j=0 never used in FMAs)
    float W[8];
    *(float4*)&W[0] = *(const float4*)&sx[xbase - 4];
    *(float4*)&W[4] = *(const float4*)&sx[xbase];

    float4 c0 = *(const float4*)hA;
    float4 c1 = *(const float4*)hB;

    #pragma unroll 4
    for (int k = 0; k < TAPS; k += 4) {
        float4 u0 = c0, u1 = c1;
        // prefetch next iteration's operands (all in-bounds by construction)
        c0 = *(const float4*)(hA + k + 4);
        c1 = *(const float4*)(hB + k + 4);
        float4 xn = *(const float4*)&sx[xbase - k - 8];

        const float* u0f = (const float*)&u0;
        const float* u1f = (const float*)&u1;
        #pragma unroll
        for (int d = 0; d < 4; ++d) {
            float cc0 = u0f[d];
            float cc1 = u1f[d];
            #pragma unroll
            for (int r = 0; r < RR; ++r) {
                float xr = W[r - d + 4];    // sx[xbase + r - (k+d)]
                acc0[r] = fmaf(xr, cc0, acc0[r]);
                acc1[r] = fmaf(xr, cc1, acc1[r]);
            }
        }
        // slide window down by 4
        W[4] = W[0]; W[5] = W[1]; W[6] = W[2]; W[7] = W[3];
        *(float4*)&W[0] = xn;
    }

    // ---- epilogue: blend and store float4 ----
    float4 o;
    float* of = (float*)&o;
    #pragma unroll
    for (int r = 0; r < RR; ++r) {
        float f = (float)(p0 + r) * (1.0f / PP);
        of[r] = acc0[r] + f * (acc1[r] - acc0[r]);
    }
    *(float4*)(out + (size_t)b * TT + t0 + 4 * tid) = o;
}

extern "C" void kernel_launch(void* const* d_in, const int* in_sizes, int n_in,
                              void* d_out, int out_size, void* d_ws, size_t ws_size,
                              hipStream_t stream) {
    const float* x = (const float*)d_in[0];
    const float* h = (const float*)d_in[1];
    float* out    = (float*)d_out;
    azdf_kernel<<<BB * CHUNKS, NTHREADS, 0, stream>>>(x, h, out);
}